// Round 12
// baseline (132.864 us; speedup 1.0000x reference)
//
#include <hip/hip_runtime.h>
#include <math.h>

#define B 4
#define H 512
#define W 1024
#define P (H*W)            // 524288
#define NI 8
#define NSEG 32            // seg = n*B + b
#define NB 512             // histogram buckets over err in [0,2]
#define INV_BW ((float)NB/2.0f)
#define NSTRIP 256
#define STRIP_PX (P/NSTRIP) // 2048
#define K1B 128             // k1 blocks per batch
#define K1PX (P/K1B)        // 4096 px per k1 block

// ---- ws layout (4-byte units) ----
#define D_CENY 0
#define D_CENX 32
#define D_PSY  64
#define D_PSX  96
#define D_CNT  128
#define D_SL   160
#define D_K4C  192          // 32 u32 last-block counters (zeroed by k2)
#define OFF_FGP 256         // 9*1024 floats (rows 0..7 = fg per inst, row 8 = bg s^2)
#define OFF_HIST (256 + 9*1024)              // u32: NSEG*NSTRIP*NB = 16.8 MB
#define OFF_FOLD (OFF_HIST + NSEG*NSTRIP*NB) // u32: 8*NSEG*NB = 512 KB
#define OFF_PK1  OFF_HIST   // pk1 (512*64 floats = 128 KB) overlaps hist:
                            // k1 writes pk1 -> k2 consumes -> k3 overwrites hist. Safe.

__device__ __forceinline__ float fast_tanh(float x) {
    float e = __expf(2.0f * x);
    return 1.0f - 2.0f / (e + 1.0f);
}
__device__ __forceinline__ float fast_sigmoid(float x) {
    return 1.0f / (1.0f + __expf(-x));
}
template<int CTRL, int RM>
__device__ __forceinline__ float dpp_add(float x) {
    int y = __builtin_amdgcn_update_dpp(0, __float_as_int(x), CTRL, RM, 0xF, true);
    return x + __int_as_float(y);
}
__device__ __forceinline__ float wred(float x) {
    x = dpp_add<0x111, 0xF>(x);   // row_shr:1
    x = dpp_add<0x112, 0xF>(x);   // row_shr:2
    x = dpp_add<0x114, 0xF>(x);   // row_shr:4
    x = dpp_add<0x118, 0xF>(x);   // row_shr:8
    x = dpp_add<0x142, 0xA>(x);   // row_bcast:15
    x = dpp_add<0x143, 0xC>(x);   // row_bcast:31
    return x;                     // lane 63 = wave total
}

// ---------------- K1: per-block partial sums (no xseed; 4 rounds of ILP) ----
__global__ __launch_bounds__(256) void k1_stats(const float* __restrict__ xv,
                                                const float* __restrict__ xs,
                                                const int*  __restrict__ t,
                                                float* __restrict__ pk1) {
    const int b = blockIdx.y, bx = blockIdx.x, tid = threadIdx.x;
    const int lane = tid & 63, wid = tid >> 6;
    const float* xv_y = xv + (size_t)b*2*P;
    const float* xv_x = xv_y + P;
    const float* xs_y = xs + (size_t)b*2*P;
    const float* xs_x = xs_y + P;
    const int*   tb   = t + (size_t)b*P;

    float cnt[NI], sey[NI], sex[NI], sgy[NI], sgx[NI], sq[NI];
    #pragma unroll
    for (int n = 0; n < NI; ++n) { cnt[n]=0.f; sey[n]=0.f; sex[n]=0.f; sgy[n]=0.f; sgx[n]=0.f; sq[n]=0.f; }

    #pragma unroll
    for (int it = 0; it < 4; ++it) {
        int p0 = bx*K1PX + it*1024 + tid*4;
        float4 vy = *(const float4*)(xv_y + p0);
        float4 vx = *(const float4*)(xv_x + p0);
        float4 sy = *(const float4*)(xs_y + p0);
        float4 sx = *(const float4*)(xs_x + p0);
        int4   tt = *(const int4*)(tb + p0);
        #pragma unroll
        for (int j = 0; j < 4; ++j) {
            int pix = p0 + j;
            float ey = fast_tanh((&vy.x)[j]) + (float)(pix >> 10) * (1.0f/1024.0f);
            float ex = fast_tanh((&vx.x)[j]) + (float)(pix & 1023) * (1.0f/1024.0f);
            float gy = (&sy.x)[j], gx = (&sx.x)[j];
            int tv = (&tt.x)[j];
            float q = gy*gy + gx*gx;
            #pragma unroll
            for (int n = 0; n < NI; ++n) {
                float m = (tv == n+1) ? 1.0f : 0.0f;
                cnt[n] += m; sey[n] += m*ey; sex[n] += m*ex;
                sgy[n] += m*gy; sgx[n] += m*gx; sq[n] += m*q;
            }
        }
    }
    __shared__ float sw[4*64];
    #define RED48(val, slot) { float r_ = wred(val); if (lane == 63) sw[wid*64 + (slot)] = r_; }
    #pragma unroll
    for (int n = 0; n < NI; ++n) {
        RED48(cnt[n], n*6+0); RED48(sey[n], n*6+1); RED48(sex[n], n*6+2);
        RED48(sgy[n], n*6+3); RED48(sgx[n], n*6+4); RED48(sq[n],  n*6+5);
    }
    #undef RED48
    __syncthreads();
    if (tid < 48) {
        float s = sw[tid] + sw[64+tid] + sw[128+tid] + sw[192+tid];
        pk1[(size_t)(b*K1B + bx)*64 + tid] = s;   // coalesced row per block
    }
}

// ---------------- K2: reduce partials + finalize params + zero counters ----------------
__global__ __launch_bounds__(1024) void k2_finalize(float* __restrict__ wsf,
                                                    const float* __restrict__ pk1,
                                                    float* __restrict__ out) {
    const int tid = threadIdx.x;
    __shared__ float part[16*64];
    __shared__ float ssum[4*64];
    const int v = tid & 63, g = tid >> 6;    // g = 0..15
    const int b = g >> 2, c = g & 3;
    float acc = 0.f;
    const int jbase = b*K1B + c*32;
    #pragma unroll 8
    for (int i = 0; i < 32; ++i) acc += pk1[(size_t)(jbase + i)*64 + v];  // coalesced
    part[g*64 + v] = acc;
    __syncthreads();
    if (tid < 256) {
        int vb = tid & 63, bb = tid >> 6;
        ssum[bb*64+vb] = part[(bb*4+0)*64+vb] + part[(bb*4+1)*64+vb]
                       + part[(bb*4+2)*64+vb] + part[(bb*4+3)*64+vb];
    }
    __syncthreads();
    if (tid < NSEG) {
        int n = tid >> 2, bb = tid & 3;      // seg = n*B + bb = tid
        float cv  = ssum[bb*64 + n*6+0];
        float sey = ssum[bb*64 + n*6+1];
        float sex = ssum[bb*64 + n*6+2];
        float sgy = ssum[bb*64 + n*6+3];
        float sgx = ssum[bb*64 + n*6+4];
        float sq  = ssum[bb*64 + n*6+5];
        float safe = fmaxf(cv, 1.0f);
        float ipy = sgy/safe, ipx = sgx/safe;
        wsf[D_CENY+tid] = sey/safe;
        wsf[D_CENX+tid] = sex/safe;
        wsf[D_PSY+tid]  = expf(10.0f*ipy);
        wsf[D_PSX+tid]  = expf(10.0f*ipx);
        wsf[D_CNT+tid]  = cv;
        wsf[D_SL+tid]   = sq/safe - (ipy*ipy + ipx*ipx);
    } else if (tid < 64) {
        ((unsigned*)wsf)[D_K4C + (tid - 32)] = 0u;   // zero last-block counters
    } else if (tid == 64) {
        out[0] = 0.f;
    }
}

// ---------------- K3: 8-instance LDS histograms, 2048-px strips (grid 1024) ----------------
__global__ __launch_bounds__(512) void k3_hist(const float* __restrict__ xv,
                                               const float* __restrict__ xseed,
                                               const int*  __restrict__ t,
                                               const float* __restrict__ wsf,
                                               unsigned* __restrict__ hist_g,
                                               float* __restrict__ fgp) {
    const int strip = blockIdx.x;
    const int b     = blockIdx.y;
    const int tid   = threadIdx.x;
    const int lane  = tid & 63;

    __shared__ unsigned hist[NI*NB];   // 16 KB: pos<<16 | neg
    {
        uint4 z = {0u,0u,0u,0u};
        #pragma unroll
        for (int i = 0; i < 2; ++i) *((uint4*)hist + i*512 + tid) = z;
    }
    __shared__ float spar[4*NI];
    if (tid < 4*NI) {
        int n = tid & (NI-1), q = tid >> 3;
        spar[tid] = wsf[q*32 + n*B + b];   // q: 0=ceny 1=cenx 2=psy 3=psx
    }
    __syncthreads();

    float ceny[NI], cenx[NI], psy[NI], psx[NI], fgn[NI];
    #pragma unroll
    for (int n = 0; n < NI; ++n) {
        ceny[n] = spar[n]; cenx[n] = spar[NI+n];
        psy[n] = spar[2*NI+n]; psx[n] = spar[3*NI+n];
        fgn[n] = 0.f;
    }
    float bgq = 0.f;

    const float* xv_y = xv + (size_t)b*2*P;
    const float* xv_x = xv_y + P;
    const float* sdp  = xseed + (size_t)b*P;
    const int*   tb   = t + (size_t)b*P;

    {   // single 2048-px iteration
        int p0 = strip * STRIP_PX + tid*4;
        float4 vy = *(const float4*)(xv_y + p0);
        float4 vx = *(const float4*)(xv_x + p0);
        float4 se = *(const float4*)(sdp + p0);
        int4   tt = *(const int4*)(tb + p0);
        #pragma unroll
        for (int j = 0; j < 4; ++j) {
            int pix = p0 + j;
            float ey = fast_tanh((&vy.x)[j]) + (float)(pix >> 10) * (1.0f/1024.0f);
            float ex = fast_tanh((&vx.x)[j]) + (float)(pix & 1023) * (1.0f/1024.0f);
            int tv = (&tt.x)[j];
            float gown = 0.f;
            #pragma unroll
            for (int n = 0; n < NI; ++n) {
                float dy = ey - ceny[n], dx = ex - cenx[n];
                float g = __expf(-0.5f * (psy[n]*dy*dy + psx[n]*dx*dx));
                bool lab = (tv == n+1);
                float err = lab ? (2.0f - 2.0f*g) : (2.0f*g);
                int key = (int)(err * INV_BW);
                key = key > (NB-1) ? (NB-1) : key;
                // key==0 counts are reconstructed exactly in K4 from totals
                if (key > 0) atomicAdd(&hist[n*NB + key], lab ? 0x10000u : 1u);
                if (lab) gown = g;
            }
            float s = fast_sigmoid((&se.x)[j]);
            if (tv > 0) {
                float d = s - gown;
                float dd = d*d;
                #pragma unroll
                for (int n = 0; n < NI; ++n) fgn[n] += (tv == n+1) ? dd : 0.f;
            } else {
                bgq += s*s;
            }
        }
    }
    __syncthreads();
    // vectorized flush: 2 x uint4 per thread
    #pragma unroll
    for (int i = 0; i < 2; ++i) {
        int lin = i*2048 + tid*4;
        int n = lin >> 9, key = lin & (NB-1);
        uint4 v = *(const uint4*)&hist[lin];
        *(uint4*)&hist_g[((size_t)((n*4 + b)*NSTRIP + strip))*NB + key] = v;
    }
    __shared__ float sfg[NI+1];
    if (tid < NI+1) sfg[tid] = 0.f;
    __syncthreads();
    #pragma unroll
    for (int n = 0; n < NI; ++n) {
        float r = wred(fgn[n]);
        if (lane == 63 && r != 0.f) atomicAdd(&sfg[n], r);   // LDS, 8-way max
    }
    {
        float r = wred(bgq);
        if (lane == 63) atomicAdd(&sfg[NI], r);
    }
    __syncthreads();
    if (tid < NI+1) fgp[tid*1024 + b*NSTRIP + strip] = sfg[tid];  // plain store
}

// ---------------- K4: fold + last-block scan + finalize (fused) ----------------
__global__ __launch_bounds__(256) void k4_fused(const unsigned* __restrict__ hist_g,
                                                unsigned* __restrict__ fold,
                                                float* __restrict__ wsf,
                                                const float* __restrict__ fgp,
                                                float* __restrict__ out) {
    const int q = blockIdx.x;            // strip quarter 0..3 (64 strips each)
    const int seg = blockIdx.y;          // 0..31
    const int tid = threadIdx.x;

    // ---- fold this quarter's 64 strips ----
    #pragma unroll
    for (int h = 0; h < 2; ++h) {
        int key = h*256 + tid;
        const unsigned* src = hist_g + (size_t)(seg*NSTRIP + q*64)*NB + key;
        unsigned pos = 0u, neg = 0u;
        #pragma unroll 8
        for (int s = 0; s < 64; ++s) {
            unsigned v = src[(size_t)s*NB];          // coalesced across threads
            pos += v >> 16; neg += v & 0xffffu;
        }
        fold[((size_t)q*NSEG + seg)*NB + key] = pos;
        fold[(size_t)4*NSEG*NB + ((size_t)q*NSEG + seg)*NB + key] = neg;
    }

    // ---- last-block election (counters zeroed by k2) ----
    __shared__ unsigned slast;
    __syncthreads();     // drains this block's fold stores
    if (tid == 0) {
        __threadfence();  // agent-scope release
        unsigned* cnt4 = (unsigned*)wsf + D_K4C;
        slast = __hip_atomic_fetch_add(&cnt4[seg], 1u, __ATOMIC_ACQ_REL,
                                       __HIP_MEMORY_SCOPE_AGENT);
    }
    __syncthreads();
    if (slast != 3u) return;
    __threadfence();      // acquire before reading other quarters' fold

    // ---- scan + finalize (one block per seg) ----
    const int n = seg >> 2, b = seg & 3;
    __shared__ float scnt[NSEG];
    __shared__ float sfr[256];
    __shared__ unsigned up[256], un[256];
    __shared__ double sdd[256];
    if (tid < NSEG) scnt[tid] = wsf[D_CNT + tid];
    __syncthreads();

    if (n == 0) {   // per-batch sigma loss + background seed loss
        sfr[tid] = fgp[NI*1024 + b*NSTRIP + tid];   // bg s^2 partials (256 strips)
        __syncthreads();
        #pragma unroll
        for (int d = 128; d > 0; d >>= 1) {
            if (tid < d) sfr[tid] += sfr[tid + d];
            __syncthreads();
        }
        if (tid == 0) {
            float bgs = sfr[0];
            int np = 0; float ss = 0.f, csum = 0.f;
            for (int k = 0; k < NI; ++k) {
                float cv = scnt[k*4 + b];
                csum += cv;
                if (cv > 0.5f) { np++; ss += wsf[D_SL + k*4 + b]; }
            }
            float bgc = fmaxf((float)P - csum, 1.0f);
            float bgl = bgs / bgc;
            float npf = fmaxf((float)np, 1.0f);
            atomicAdd(out, (ss/npf + bgl/(1.0f + (float)np)) * (1.0f/(float)B));
        }
        __syncthreads();
    }

    const float G = scnt[seg];
    if (G < 0.5f) return;   // uniform across block
    int npc = 0;
    #pragma unroll
    for (int k = 0; k < NI; ++k) npc += (scnt[k*4 + b] > 0.5f) ? 1 : 0;

    // fg seed partial reduce (256 strips)
    sfr[tid] = fgp[n*1024 + b*NSTRIP + tid];
    __syncthreads();
    #pragma unroll
    for (int d = 128; d > 0; d >>= 1) {
        if (tid < d) sfr[tid] += sfr[tid + d];
        __syncthreads();
    }
    const float FG = sfr[0];

    // thread t owns keys 2t, 2t+1: sum the 4 quarter-partials
    unsigned pos2[2] = {0u,0u}, neg2[2] = {0u,0u};
    #pragma unroll
    for (int qq = 0; qq < 4; ++qq) {
        uint2 pv = *((const uint2*)(fold + ((size_t)qq*NSEG + seg)*NB) + tid);
        uint2 nv = *((const uint2*)(fold + (size_t)4*NSEG*NB + ((size_t)qq*NSEG + seg)*NB) + tid);
        pos2[0] += pv.x; pos2[1] += pv.y;
        neg2[0] += nv.x; neg2[1] += nv.y;
    }
    unsigned tp = pos2[0] + pos2[1];
    unsigned tn = neg2[0] + neg2[1];

    // suffix (descending-key) inclusive scan over thread totals
    up[tid] = tp; un[tid] = tn;
    __syncthreads();
    for (int d = 1; d < 256; d <<= 1) {
        unsigned ap = (tid + d < 256) ? up[tid + d] : 0u;
        unsigned an = (tid + d < 256) ? un[tid + d] : 0u;
        __syncthreads();
        up[tid] += ap; un[tid] += an;
        __syncthreads();
    }
    const unsigned TP = up[0], TN = un[0];
    const unsigned Gu = (unsigned)(G + 0.5f);
    const unsigned NEGu = (unsigned)P - Gu;
    unsigned cump = up[tid] - tp;   // counts with key strictly greater
    unsigned cumn = un[tid] - tn;

    const double dG = (double)G;
    double acc = 0.0;
    #pragma unroll
    for (int j = 1; j >= 0; --j) {
        unsigned cp = pos2[j], cn = neg2[j];
        int key = tid*2 + j;
        if (tid == 0 && j == 0) { cp = Gu - TP; cn = NEGu - TN; }  // exact bucket-0
        if (cp | cn) {
            unsigned ep = cump, en = cumn;
            unsigned epi = ep + cp, eni = en + cn;
            double jb = 1.0 - (dG - (double)ep)  / (dG + (double)en);
            double ja = 1.0 - (dG - (double)epi) / (dG + (double)eni);
            acc += (((double)key + 0.5) * (2.0/(double)NB)) * (ja - jb);
        }
        cump += cp; cumn += cn;
    }
    sdd[tid] = acc;
    __syncthreads();
    #pragma unroll
    for (int d = 128; d > 0; d >>= 1) {
        if (tid < d) sdd[tid] += sdd[tid + d];
        __syncthreads();
    }
    if (tid == 0) {
        float npf = fmaxf((float)npc, 1.0f);
        float val = (float)sdd[0] / (npf * (float)B)
                  + (FG / G) / ((1.0f + (float)npc) * (float)B);
        atomicAdd(out, val);
    }
}

extern "C" void kernel_launch(void* const* d_in, const int* in_sizes, int n_in,
                              void* d_out, int out_size, void* d_ws, size_t ws_size,
                              hipStream_t stream) {
    (void)in_sizes; (void)n_in; (void)out_size; (void)ws_size;
    const float* xv  = (const float*)d_in[0];
    const float* xs  = (const float*)d_in[1];
    const float* xsd = (const float*)d_in[2];
    const int*   t   = (const int*)d_in[3];
    float* wsf = (float*)d_ws;
    unsigned* hist_g = (unsigned*)d_ws + OFF_HIST;
    unsigned* fold   = (unsigned*)d_ws + OFF_FOLD;
    float* pk1 = wsf + OFF_PK1;
    float* fgp = wsf + OFF_FGP;
    float* out = (float*)d_out;

    k1_stats<<<dim3(K1B, B), 256, 0, stream>>>(xv, xs, t, pk1);
    k2_finalize<<<1, 1024, 0, stream>>>(wsf, pk1, out);
    k3_hist<<<dim3(NSTRIP, B), 512, 0, stream>>>(xv, xsd, t, wsf, hist_g, fgp);
    k4_fused<<<dim3(4, NSEG), 256, 0, stream>>>(hist_g, fold, wsf, fgp, out);
}

// Round 13
// 132.572 us; speedup vs baseline: 1.0022x; 1.0022x over previous
//
#include <hip/hip_runtime.h>
#include <math.h>

#define B 4
#define H 512
#define W 1024
#define P (H*W)            // 524288
#define NI 8
#define NSEG 32            // seg = n*B + b
#define NB 256             // histogram buckets over err in [0,2]
#define INV_BW ((float)NB/2.0f)
#define NSTRIP 256
#define STRIP_PX (P/NSTRIP) // 2048
#define K1B 512             // k1 blocks per batch -> 2048 blocks, 8/CU
#define K1PX (P/K1B)        // 1024 px per k1 block

// ---- ws layout (4-byte units) ----
#define D_CENY 0
#define D_CENX 32
#define D_PSY  64
#define D_PSX  96
#define D_CNT  128
#define D_SL   160
#define D_K4C  192          // 32 u32 last-block counters (zeroed by k2)
#define OFF_FGP 256         // 9*1024 floats (rows 0..7 = fg per inst, row 8 = bg s^2)
#define OFF_HIST (OFF_FGP + 9*1024)          // u32: NSEG*NSTRIP*NB = 8 MB
#define OFF_FOLD (OFF_HIST + NSEG*NSTRIP*NB) // u32: 8*NSEG*NB = 256 KB
#define OFF_PK1  (OFF_FOLD + 8*NSEG*NB)      // 2048*64 floats = 512 KB

__device__ __forceinline__ float fast_tanh(float x) {
    float e = __expf(2.0f * x);
    return 1.0f - 2.0f / (e + 1.0f);
}
__device__ __forceinline__ float fast_sigmoid(float x) {
    return 1.0f / (1.0f + __expf(-x));
}
template<int CTRL, int RM>
__device__ __forceinline__ float dpp_add(float x) {
    int y = __builtin_amdgcn_update_dpp(0, __float_as_int(x), CTRL, RM, 0xF, true);
    return x + __int_as_float(y);
}
__device__ __forceinline__ float wred(float x) {
    x = dpp_add<0x111, 0xF>(x);   // row_shr:1
    x = dpp_add<0x112, 0xF>(x);   // row_shr:2
    x = dpp_add<0x114, 0xF>(x);   // row_shr:4
    x = dpp_add<0x118, 0xF>(x);   // row_shr:8
    x = dpp_add<0x142, 0xA>(x);   // row_bcast:15
    x = dpp_add<0x143, 0xC>(x);   // row_bcast:31
    return x;                     // lane 63 = wave total
}

// ---------------- K1: per-block partial sums (2048 blocks, 8/CU) ----
__global__ __launch_bounds__(256) void k1_stats(const float* __restrict__ xv,
                                                const float* __restrict__ xs,
                                                const int*  __restrict__ t,
                                                float* __restrict__ pk1) {
    const int b = blockIdx.y, bx = blockIdx.x, tid = threadIdx.x;
    const int lane = tid & 63, wid = tid >> 6;
    const float* xv_y = xv + (size_t)b*2*P;
    const float* xv_x = xv_y + P;
    const float* xs_y = xs + (size_t)b*2*P;
    const float* xs_x = xs_y + P;
    const int*   tb   = t + (size_t)b*P;

    float cnt[NI], sey[NI], sex[NI], sgy[NI], sgx[NI], sq[NI];
    #pragma unroll
    for (int n = 0; n < NI; ++n) { cnt[n]=0.f; sey[n]=0.f; sex[n]=0.f; sgy[n]=0.f; sgx[n]=0.f; sq[n]=0.f; }

    int p0 = bx*K1PX + tid*4;
    float4 vy = *(const float4*)(xv_y + p0);
    float4 vx = *(const float4*)(xv_x + p0);
    float4 sy = *(const float4*)(xs_y + p0);
    float4 sx = *(const float4*)(xs_x + p0);
    int4   tt = *(const int4*)(tb + p0);
    #pragma unroll
    for (int j = 0; j < 4; ++j) {
        int pix = p0 + j;
        float ey = fast_tanh((&vy.x)[j]) + (float)(pix >> 10) * (1.0f/1024.0f);
        float ex = fast_tanh((&vx.x)[j]) + (float)(pix & 1023) * (1.0f/1024.0f);
        float gy = (&sy.x)[j], gx = (&sx.x)[j];
        int tv = (&tt.x)[j];
        float q = gy*gy + gx*gx;
        #pragma unroll
        for (int n = 0; n < NI; ++n) {
            float m = (tv == n+1) ? 1.0f : 0.0f;
            cnt[n] += m; sey[n] += m*ey; sex[n] += m*ex;
            sgy[n] += m*gy; sgx[n] += m*gx; sq[n] += m*q;
        }
    }
    __shared__ float sw[4*64];
    #define RED48(val, slot) { float r_ = wred(val); if (lane == 63) sw[wid*64 + (slot)] = r_; }
    #pragma unroll
    for (int n = 0; n < NI; ++n) {
        RED48(cnt[n], n*6+0); RED48(sey[n], n*6+1); RED48(sex[n], n*6+2);
        RED48(sgy[n], n*6+3); RED48(sgx[n], n*6+4); RED48(sq[n],  n*6+5);
    }
    #undef RED48
    __syncthreads();
    if (tid < 48) {
        float s = sw[tid] + sw[64+tid] + sw[128+tid] + sw[192+tid];
        pk1[(size_t)(b*K1B + bx)*64 + tid] = s;   // coalesced row per block
    }
}

// ---------------- K2: reduce partials + finalize params + zero counters ----------------
__global__ __launch_bounds__(1024) void k2_finalize(float* __restrict__ wsf,
                                                    const float* __restrict__ pk1,
                                                    float* __restrict__ out) {
    const int tid = threadIdx.x;
    __shared__ float part[16*64];
    __shared__ float ssum[4*64];
    const int v = tid & 63, g = tid >> 6;    // g = 0..15
    const int b = g >> 2, c = g & 3;
    float acc = 0.f;
    const int jbase = b*K1B + c*128;
    #pragma unroll 8
    for (int i = 0; i < 128; ++i) acc += pk1[(size_t)(jbase + i)*64 + v];  // coalesced
    part[g*64 + v] = acc;
    __syncthreads();
    if (tid < 256) {
        int vb = tid & 63, bb = tid >> 6;
        ssum[bb*64+vb] = part[(bb*4+0)*64+vb] + part[(bb*4+1)*64+vb]
                       + part[(bb*4+2)*64+vb] + part[(bb*4+3)*64+vb];
    }
    __syncthreads();
    if (tid < NSEG) {
        int n = tid >> 2, bb = tid & 3;      // seg = n*B + bb = tid
        float cv  = ssum[bb*64 + n*6+0];
        float sey = ssum[bb*64 + n*6+1];
        float sex = ssum[bb*64 + n*6+2];
        float sgy = ssum[bb*64 + n*6+3];
        float sgx = ssum[bb*64 + n*6+4];
        float sq  = ssum[bb*64 + n*6+5];
        float safe = fmaxf(cv, 1.0f);
        float ipy = sgy/safe, ipx = sgx/safe;
        wsf[D_CENY+tid] = sey/safe;
        wsf[D_CENX+tid] = sex/safe;
        wsf[D_PSY+tid]  = expf(10.0f*ipy);
        wsf[D_PSX+tid]  = expf(10.0f*ipx);
        wsf[D_CNT+tid]  = cv;
        wsf[D_SL+tid]   = sq/safe - (ipy*ipy + ipx*ipx);
    } else if (tid < 64) {
        ((unsigned*)wsf)[D_K4C + (tid - 32)] = 0u;   // zero last-block counters
    } else if (tid == 64) {
        out[0] = 0.f;
    }
}

// ---------------- K3: 8-instance LDS histograms (8 KB), 2048-px strips ----------------
__global__ __launch_bounds__(512) void k3_hist(const float* __restrict__ xv,
                                               const float* __restrict__ xseed,
                                               const int*  __restrict__ t,
                                               const float* __restrict__ wsf,
                                               unsigned* __restrict__ hist_g,
                                               float* __restrict__ fgp) {
    const int strip = blockIdx.x;
    const int b     = blockIdx.y;
    const int tid   = threadIdx.x;
    const int lane  = tid & 63;

    __shared__ unsigned hist[NI*NB];   // 8 KB: pos<<16 | neg
    *((uint4*)hist + tid) = (uint4){0u,0u,0u,0u};
    __shared__ float spar[4*NI];
    if (tid < 4*NI) {
        int n = tid & (NI-1), q = tid >> 3;
        spar[tid] = wsf[q*32 + n*B + b];   // q: 0=ceny 1=cenx 2=psy 3=psx
    }
    __syncthreads();

    float ceny[NI], cenx[NI], psy[NI], psx[NI], fgn[NI];
    #pragma unroll
    for (int n = 0; n < NI; ++n) {
        ceny[n] = spar[n]; cenx[n] = spar[NI+n];
        psy[n] = spar[2*NI+n]; psx[n] = spar[3*NI+n];
        fgn[n] = 0.f;
    }
    float bgq = 0.f;

    const float* xv_y = xv + (size_t)b*2*P;
    const float* xv_x = xv_y + P;
    const float* sdp  = xseed + (size_t)b*P;
    const int*   tb   = t + (size_t)b*P;

    {   // single 2048-px iteration
        int p0 = strip * STRIP_PX + tid*4;
        float4 vy = *(const float4*)(xv_y + p0);
        float4 vx = *(const float4*)(xv_x + p0);
        float4 se = *(const float4*)(sdp + p0);
        int4   tt = *(const int4*)(tb + p0);
        #pragma unroll
        for (int j = 0; j < 4; ++j) {
            int pix = p0 + j;
            float ey = fast_tanh((&vy.x)[j]) + (float)(pix >> 10) * (1.0f/1024.0f);
            float ex = fast_tanh((&vx.x)[j]) + (float)(pix & 1023) * (1.0f/1024.0f);
            int tv = (&tt.x)[j];
            float gown = 0.f;
            #pragma unroll
            for (int n = 0; n < NI; ++n) {
                float dy = ey - ceny[n], dx = ex - cenx[n];
                float g = __expf(-0.5f * (psy[n]*dy*dy + psx[n]*dx*dx));
                bool lab = (tv == n+1);
                float err = lab ? (2.0f - 2.0f*g) : (2.0f*g);
                int key = (int)(err * INV_BW);
                key = key > (NB-1) ? (NB-1) : key;
                // key==0 counts are reconstructed exactly in K4 from totals
                if (key > 0) atomicAdd(&hist[n*NB + key], lab ? 0x10000u : 1u);
                if (lab) gown = g;
            }
            float s = fast_sigmoid((&se.x)[j]);
            if (tv > 0) {
                float d = s - gown;
                float dd = d*d;
                #pragma unroll
                for (int n = 0; n < NI; ++n) fgn[n] += (tv == n+1) ? dd : 0.f;
            } else {
                bgq += s*s;
            }
        }
    }
    __syncthreads();
    // vectorized flush: 1 uint4 per thread (2048 u32 total)
    {
        int lin = tid*4;
        int n = lin >> 8, key = lin & (NB-1);
        uint4 v = *(const uint4*)&hist[lin];
        *(uint4*)&hist_g[((size_t)((n*4 + b)*NSTRIP + strip))*NB + key] = v;
    }
    __shared__ float sfg[NI+1];
    if (tid < NI+1) sfg[tid] = 0.f;
    __syncthreads();
    #pragma unroll
    for (int n = 0; n < NI; ++n) {
        float r = wred(fgn[n]);
        if (lane == 63 && r != 0.f) atomicAdd(&sfg[n], r);   // LDS, 8-way max
    }
    {
        float r = wred(bgq);
        if (lane == 63) atomicAdd(&sfg[NI], r);
    }
    __syncthreads();
    if (tid < NI+1) fgp[tid*1024 + b*NSTRIP + strip] = sfg[tid];  // plain store
}

// ---------------- K4: fold + last-block scan + finalize (fused) ----------------
__global__ __launch_bounds__(256) void k4_fused(const unsigned* __restrict__ hist_g,
                                                unsigned* __restrict__ fold,
                                                float* __restrict__ wsf,
                                                const float* __restrict__ fgp,
                                                float* __restrict__ out) {
    const int q = blockIdx.x;            // strip quarter 0..3 (64 strips each)
    const int seg = blockIdx.y;          // 0..31
    const int tid = threadIdx.x;         // owns key = tid (NB == 256)

    // ---- fold this quarter's 64 strips ----
    unsigned posk, negk;
    {
        const unsigned* src = hist_g + (size_t)(seg*NSTRIP + q*64)*NB + tid;
        unsigned pos = 0u, neg = 0u;
        #pragma unroll 8
        for (int s = 0; s < 64; ++s) {
            unsigned v = src[(size_t)s*NB];          // coalesced across threads
            pos += v >> 16; neg += v & 0xffffu;
        }
        fold[((size_t)q*NSEG + seg)*NB + tid] = pos;
        fold[(size_t)4*NSEG*NB + ((size_t)q*NSEG + seg)*NB + tid] = neg;
        posk = pos; negk = neg;
    }

    // ---- last-block election (counters zeroed by k2) ----
    __shared__ unsigned slast;
    __syncthreads();     // drains this block's fold stores
    if (tid == 0) {
        __threadfence();  // agent-scope release
        unsigned* cnt4 = (unsigned*)wsf + D_K4C;
        slast = __hip_atomic_fetch_add(&cnt4[seg], 1u, __ATOMIC_ACQ_REL,
                                       __HIP_MEMORY_SCOPE_AGENT);
    }
    __syncthreads();
    if (slast != 3u) return;
    __threadfence();      // acquire before reading other quarters' fold

    // ---- scan + finalize (one block per seg) ----
    const int n = seg >> 2, b = seg & 3;
    __shared__ float scnt[NSEG];
    __shared__ float sfr[256];
    __shared__ unsigned up[256], un[256];
    __shared__ double sdd[256];
    if (tid < NSEG) scnt[tid] = wsf[D_CNT + tid];
    __syncthreads();

    if (n == 0) {   // per-batch sigma loss + background seed loss
        sfr[tid] = fgp[NI*1024 + b*NSTRIP + tid];   // bg s^2 partials (256 strips)
        __syncthreads();
        #pragma unroll
        for (int d = 128; d > 0; d >>= 1) {
            if (tid < d) sfr[tid] += sfr[tid + d];
            __syncthreads();
        }
        if (tid == 0) {
            float bgs = sfr[0];
            int np = 0; float ss = 0.f, csum = 0.f;
            for (int k = 0; k < NI; ++k) {
                float cv = scnt[k*4 + b];
                csum += cv;
                if (cv > 0.5f) { np++; ss += wsf[D_SL + k*4 + b]; }
            }
            float bgc = fmaxf((float)P - csum, 1.0f);
            float bgl = bgs / bgc;
            float npf = fmaxf((float)np, 1.0f);
            atomicAdd(out, (ss/npf + bgl/(1.0f + (float)np)) * (1.0f/(float)B));
        }
        __syncthreads();
    }

    const float G = scnt[seg];
    if (G < 0.5f) return;   // uniform across block
    int npc = 0;
    #pragma unroll
    for (int k = 0; k < NI; ++k) npc += (scnt[k*4 + b] > 0.5f) ? 1 : 0;

    // fg seed partial reduce (256 strips)
    sfr[tid] = fgp[n*1024 + b*NSTRIP + tid];
    __syncthreads();
    #pragma unroll
    for (int d = 128; d > 0; d >>= 1) {
        if (tid < d) sfr[tid] += sfr[tid + d];
        __syncthreads();
    }
    const float FG = sfr[0];

    // thread t owns key t: sum this quarter's regs + other 3 quarters' folds
    unsigned pos = posk, neg = negk;
    #pragma unroll
    for (int qq = 0; qq < 4; ++qq) {
        if (qq == q) continue;
        pos += fold[((size_t)qq*NSEG + seg)*NB + tid];
        neg += fold[(size_t)4*NSEG*NB + ((size_t)qq*NSEG + seg)*NB + tid];
    }

    // suffix (descending-key) inclusive scan over thread totals
    up[tid] = pos; un[tid] = neg;
    __syncthreads();
    for (int d = 1; d < 256; d <<= 1) {
        unsigned ap = (tid + d < 256) ? up[tid + d] : 0u;
        unsigned an = (tid + d < 256) ? un[tid + d] : 0u;
        __syncthreads();
        up[tid] += ap; un[tid] += an;
        __syncthreads();
    }
    const unsigned TP = up[0], TN = un[0];
    const unsigned Gu = (unsigned)(G + 0.5f);
    const unsigned NEGu = (unsigned)P - Gu;
    unsigned cump = up[tid] - pos;   // counts with key strictly greater
    unsigned cumn = un[tid] - neg;

    const double dG = (double)G;
    double acc = 0.0;
    {
        unsigned cp = pos, cn = neg;
        if (tid == 0) { cp = Gu - TP; cn = NEGu - TN; }  // exact bucket-0
        if (cp | cn) {
            unsigned ep = cump, en = cumn;
            unsigned epi = ep + cp, eni = en + cn;
            double jb = 1.0 - (dG - (double)ep)  / (dG + (double)en);
            double ja = 1.0 - (dG - (double)epi) / (dG + (double)eni);
            acc = (((double)tid + 0.5) * (2.0/(double)NB)) * (ja - jb);
        }
    }
    sdd[tid] = acc;
    __syncthreads();
    #pragma unroll
    for (int d = 128; d > 0; d >>= 1) {
        if (tid < d) sdd[tid] += sdd[tid + d];
        __syncthreads();
    }
    if (tid == 0) {
        float npf = fmaxf((float)npc, 1.0f);
        float val = (float)sdd[0] / (npf * (float)B)
                  + (FG / G) / ((1.0f + (float)npc) * (float)B);
        atomicAdd(out, val);
    }
}

extern "C" void kernel_launch(void* const* d_in, const int* in_sizes, int n_in,
                              void* d_out, int out_size, void* d_ws, size_t ws_size,
                              hipStream_t stream) {
    (void)in_sizes; (void)n_in; (void)out_size; (void)ws_size;
    const float* xv  = (const float*)d_in[0];
    const float* xs  = (const float*)d_in[1];
    const float* xsd = (const float*)d_in[2];
    const int*   t   = (const int*)d_in[3];
    float* wsf = (float*)d_ws;
    unsigned* hist_g = (unsigned*)d_ws + OFF_HIST;
    unsigned* fold   = (unsigned*)d_ws + OFF_FOLD;
    float* pk1 = wsf + OFF_PK1;
    float* fgp = wsf + OFF_FGP;
    float* out = (float*)d_out;

    k1_stats<<<dim3(K1B, B), 256, 0, stream>>>(xv, xs, t, pk1);
    k2_finalize<<<1, 1024, 0, stream>>>(wsf, pk1, out);
    k3_hist<<<dim3(NSTRIP, B), 512, 0, stream>>>(xv, xsd, t, wsf, hist_g, fgp);
    k4_fused<<<dim3(4, NSEG), 256, 0, stream>>>(hist_g, fold, wsf, fgp, out);
}

// Round 14
// 128.581 us; speedup vs baseline: 1.0333x; 1.0310x over previous
//
#include <hip/hip_runtime.h>
#include <math.h>

#define B 4
#define H 512
#define W 1024
#define P (H*W)            // 524288
#define NI 8
#define NSEG 32            // seg = n*B + b
#define NB 256             // histogram buckets over err in [0,2]
#define NSTRIP 256
#define STRIP_PX (P/NSTRIP) // 2048
#define K1B 128             // k1 blocks per batch
#define K1PX (P/K1B)        // 4096 px per k1 block

// ---- ws layout (4-byte units) ----
#define D_CYP  0            // ay*ceny
#define D_CXP  32           // ax*cenx
#define D_AY   64           // sqrt(0.72135*psy)
#define D_AX   96           // sqrt(0.72135*psx)
#define D_CNT  128
#define D_SL   160
#define D_K4C  192          // 32 u32 last-block counters (zeroed by k2)
#define OFF_FGP 256         // 9*1024 floats (rows 0..7 = fg per inst, row 8 = bg s^2)
#define OFF_HIST (OFF_FGP + 9*1024)          // u32: NSEG*NSTRIP*NB = 8 MB
#define OFF_FOLD (OFF_HIST + NSEG*NSTRIP*NB) // u32: 8*NSEG*NB = 256 KB
#define OFF_PK1  (OFF_FOLD + 8*NSEG*NB)      // 512*64 floats = 128 KB

__device__ __forceinline__ float fast_tanh(float x) {
    float e = __expf(2.0f * x);
    return 1.0f - 2.0f / (e + 1.0f);
}
__device__ __forceinline__ float fast_sigmoid(float x) {
    return 1.0f / (1.0f + __expf(-x));
}
template<int CTRL, int RM>
__device__ __forceinline__ float dpp_add(float x) {
    int y = __builtin_amdgcn_update_dpp(0, __float_as_int(x), CTRL, RM, 0xF, true);
    return x + __int_as_float(y);
}
__device__ __forceinline__ float wred(float x) {
    x = dpp_add<0x111, 0xF>(x);   // row_shr:1
    x = dpp_add<0x112, 0xF>(x);   // row_shr:2
    x = dpp_add<0x114, 0xF>(x);   // row_shr:4
    x = dpp_add<0x118, 0xF>(x);   // row_shr:8
    x = dpp_add<0x142, 0xA>(x);   // row_bcast:15
    x = dpp_add<0x143, 0xC>(x);   // row_bcast:31
    return x;                     // lane 63 = wave total
}

// ---------------- K1: per-block partial sums (512 blocks, 4 rounds ILP) ----
__global__ __launch_bounds__(256) void k1_stats(const float* __restrict__ xv,
                                                const float* __restrict__ xs,
                                                const int*  __restrict__ t,
                                                float* __restrict__ pk1) {
    const int b = blockIdx.y, bx = blockIdx.x, tid = threadIdx.x;
    const int lane = tid & 63, wid = tid >> 6;
    const float* xv_y = xv + (size_t)b*2*P;
    const float* xv_x = xv_y + P;
    const float* xs_y = xs + (size_t)b*2*P;
    const float* xs_x = xs_y + P;
    const int*   tb   = t + (size_t)b*P;

    float cnt[NI], sey[NI], sex[NI], sgy[NI], sgx[NI], sq[NI];
    #pragma unroll
    for (int n = 0; n < NI; ++n) { cnt[n]=0.f; sey[n]=0.f; sex[n]=0.f; sgy[n]=0.f; sgx[n]=0.f; sq[n]=0.f; }

    #pragma unroll
    for (int it = 0; it < 4; ++it) {
        int p0 = bx*K1PX + it*1024 + tid*4;
        float4 vy = *(const float4*)(xv_y + p0);
        float4 vx = *(const float4*)(xv_x + p0);
        float4 sy = *(const float4*)(xs_y + p0);
        float4 sx = *(const float4*)(xs_x + p0);
        int4   tt = *(const int4*)(tb + p0);
        #pragma unroll
        for (int j = 0; j < 4; ++j) {
            int pix = p0 + j;
            float ey = fast_tanh((&vy.x)[j]) + (float)(pix >> 10) * (1.0f/1024.0f);
            float ex = fast_tanh((&vx.x)[j]) + (float)(pix & 1023) * (1.0f/1024.0f);
            float gy = (&sy.x)[j], gx = (&sx.x)[j];
            int tv = (&tt.x)[j];
            float q = gy*gy + gx*gx;
            #pragma unroll
            for (int n = 0; n < NI; ++n) {
                float m = (tv == n+1) ? 1.0f : 0.0f;
                cnt[n] += m; sey[n] += m*ey; sex[n] += m*ex;
                sgy[n] += m*gy; sgx[n] += m*gx; sq[n] += m*q;
            }
        }
    }
    __shared__ float sw[4*64];
    #define RED48(val, slot) { float r_ = wred(val); if (lane == 63) sw[wid*64 + (slot)] = r_; }
    #pragma unroll
    for (int n = 0; n < NI; ++n) {
        RED48(cnt[n], n*6+0); RED48(sey[n], n*6+1); RED48(sex[n], n*6+2);
        RED48(sgy[n], n*6+3); RED48(sgx[n], n*6+4); RED48(sq[n],  n*6+5);
    }
    #undef RED48
    __syncthreads();
    if (tid < 48) {
        float s = sw[tid] + sw[64+tid] + sw[128+tid] + sw[192+tid];
        pk1[(size_t)(b*K1B + bx)*64 + tid] = s;   // coalesced row per block
    }
}

// ---------------- K2: reduce partials + finalize params + zero counters ----------------
__global__ __launch_bounds__(1024) void k2_finalize(float* __restrict__ wsf,
                                                    const float* __restrict__ pk1,
                                                    float* __restrict__ out) {
    const int tid = threadIdx.x;
    __shared__ float part[16*64];
    __shared__ float ssum[4*64];
    const int v = tid & 63, g = tid >> 6;    // g = 0..15
    const int b = g >> 2, c = g & 3;
    float acc = 0.f;
    const int jbase = b*K1B + c*32;
    #pragma unroll 8
    for (int i = 0; i < 32; ++i) acc += pk1[(size_t)(jbase + i)*64 + v];  // coalesced
    part[g*64 + v] = acc;
    __syncthreads();
    if (tid < 256) {
        int vb = tid & 63, bb = tid >> 6;
        ssum[bb*64+vb] = part[(bb*4+0)*64+vb] + part[(bb*4+1)*64+vb]
                       + part[(bb*4+2)*64+vb] + part[(bb*4+3)*64+vb];
    }
    __syncthreads();
    if (tid < NSEG) {
        int n = tid >> 2, bb = tid & 3;      // seg = n*B + bb = tid
        float cv  = ssum[bb*64 + n*6+0];
        float sey = ssum[bb*64 + n*6+1];
        float sex = ssum[bb*64 + n*6+2];
        float sgy = ssum[bb*64 + n*6+3];
        float sgx = ssum[bb*64 + n*6+4];
        float sq  = ssum[bb*64 + n*6+5];
        float safe = fmaxf(cv, 1.0f);
        float ipy = sgy/safe, ipx = sgx/safe;
        float ceny = sey/safe, cenx = sex/safe;
        // fold 0.5*log2(e) into per-instance scales: e = (ay*dy)^2 + (ax*dx)^2
        const float hl2e = 0.7213475204444817f;
        float ay = sqrtf(expf(10.0f*ipy) * hl2e);
        float ax = sqrtf(expf(10.0f*ipx) * hl2e);
        wsf[D_AY+tid]  = ay;
        wsf[D_AX+tid]  = ax;
        wsf[D_CYP+tid] = ay*ceny;
        wsf[D_CXP+tid] = ax*cenx;
        wsf[D_CNT+tid] = cv;
        wsf[D_SL+tid]  = sq/safe - (ipy*ipy + ipx*ipx);
    } else if (tid < 64) {
        ((unsigned*)wsf)[D_K4C + (tid - 32)] = 0u;   // zero last-block counters
    } else if (tid == 64) {
        out[0] = 0.f;
    }
}

// ---------------- K3: 8-instance LDS histograms (8 KB), strength-reduced ----------------
__global__ __launch_bounds__(512) void k3_hist(const float* __restrict__ xv,
                                               const float* __restrict__ xseed,
                                               const int*  __restrict__ t,
                                               const float* __restrict__ wsf,
                                               unsigned* __restrict__ hist_g,
                                               float* __restrict__ fgp) {
    const int strip = blockIdx.x;
    const int b     = blockIdx.y;
    const int tid   = threadIdx.x;
    const int lane  = tid & 63;

    __shared__ unsigned hist[NI*NB];   // 8 KB: pos<<16 | neg
    *((uint4*)hist + tid) = (uint4){0u,0u,0u,0u};
    __shared__ float spar[4*NI];
    if (tid < 4*NI) {
        int n = tid & (NI-1), q = tid >> 3;
        spar[tid] = wsf[q*32 + n*B + b];   // q: 0=cyp 1=cxp 2=ay 3=ax
    }
    __syncthreads();

    float cyp[NI], cxp[NI], ay[NI], ax[NI], fgn[NI];
    #pragma unroll
    for (int n = 0; n < NI; ++n) {
        cyp[n] = spar[n]; cxp[n] = spar[NI+n];
        ay[n] = spar[2*NI+n]; ax[n] = spar[3*NI+n];
        fgn[n] = 0.f;
    }
    float bgq = 0.f;

    const float* xv_y = xv + (size_t)b*2*P;
    const float* xv_x = xv_y + P;
    const float* sdp  = xseed + (size_t)b*P;
    const int*   tb   = t + (size_t)b*P;

    {   // single 2048-px iteration
        int p0 = strip * STRIP_PX + tid*4;
        float4 vy = *(const float4*)(xv_y + p0);
        float4 vx = *(const float4*)(xv_x + p0);
        float4 se = *(const float4*)(sdp + p0);
        int4   tt = *(const int4*)(tb + p0);
        #pragma unroll
        for (int j = 0; j < 4; ++j) {
            int pix = p0 + j;
            float ey = fast_tanh((&vy.x)[j]) + (float)(pix >> 10) * (1.0f/1024.0f);
            float ex = fast_tanh((&vx.x)[j]) + (float)(pix & 1023) * (1.0f/1024.0f);
            int tv = (&tt.x)[j];
            float gown = 0.f;
            #pragma unroll
            for (int n = 0; n < NI; ++n) {
                float dyp = fmaf(ey, ay[n], -cyp[n]);
                float dxp = fmaf(ex, ax[n], -cxp[n]);
                float e = fmaf(dxp, dxp, dyp*dyp);      // 0.72135 * dist
                float kg = exp2f(8.0f - e);             // 256 * g
                bool lab = (tv == n+1);
                float sel = lab ? (256.0f - kg) : kg;   // == err*INV_BW exactly
                int key = (int)sel;
                key = key > (NB-1) ? (NB-1) : key;
                // key==0 counts are reconstructed exactly in K4 from totals
                if (key > 0) atomicAdd(&hist[n*NB + key], lab ? 0x10000u : 1u);
                if (lab) gown = kg * 0.00390625f;
            }
            float s = fast_sigmoid((&se.x)[j]);
            if (tv > 0) {
                float d = s - gown;
                float dd = d*d;
                #pragma unroll
                for (int n = 0; n < NI; ++n) fgn[n] += (tv == n+1) ? dd : 0.f;
            } else {
                bgq += s*s;
            }
        }
    }
    __syncthreads();
    // vectorized flush: 1 uint4 per thread (2048 u32 total)
    {
        int lin = tid*4;
        int n = lin >> 8, key = lin & (NB-1);
        uint4 v = *(const uint4*)&hist[lin];
        *(uint4*)&hist_g[((size_t)((n*4 + b)*NSTRIP + strip))*NB + key] = v;
    }
    __shared__ float sfg[NI+1];
    if (tid < NI+1) sfg[tid] = 0.f;
    __syncthreads();
    #pragma unroll
    for (int n = 0; n < NI; ++n) {
        float r = wred(fgn[n]);
        if (lane == 63 && r != 0.f) atomicAdd(&sfg[n], r);   // LDS, 8-way max
    }
    {
        float r = wred(bgq);
        if (lane == 63) atomicAdd(&sfg[NI], r);
    }
    __syncthreads();
    if (tid < NI+1) fgp[tid*1024 + b*NSTRIP + strip] = sfg[tid];  // plain store
}

// ---------------- K4: fold + last-block scan + finalize (fused) ----------------
__global__ __launch_bounds__(256) void k4_fused(const unsigned* __restrict__ hist_g,
                                                unsigned* __restrict__ fold,
                                                float* __restrict__ wsf,
                                                const float* __restrict__ fgp,
                                                float* __restrict__ out) {
    const int q = blockIdx.x;            // strip quarter 0..3 (64 strips each)
    const int seg = blockIdx.y;          // 0..31
    const int tid = threadIdx.x;         // owns key = tid (NB == 256)

    // ---- fold this quarter's 64 strips ----
    unsigned posk, negk;
    {
        const unsigned* src = hist_g + (size_t)(seg*NSTRIP + q*64)*NB + tid;
        unsigned pos = 0u, neg = 0u;
        #pragma unroll 8
        for (int s = 0; s < 64; ++s) {
            unsigned v = src[(size_t)s*NB];          // coalesced across threads
            pos += v >> 16; neg += v & 0xffffu;
        }
        fold[((size_t)q*NSEG + seg)*NB + tid] = pos;
        fold[(size_t)4*NSEG*NB + ((size_t)q*NSEG + seg)*NB + tid] = neg;
        posk = pos; negk = neg;
    }

    // ---- last-block election (counters zeroed by k2) ----
    __shared__ unsigned slast;
    __syncthreads();     // drains this block's fold stores
    if (tid == 0) {
        __threadfence();  // agent-scope release
        unsigned* cnt4 = (unsigned*)wsf + D_K4C;
        slast = __hip_atomic_fetch_add(&cnt4[seg], 1u, __ATOMIC_ACQ_REL,
                                       __HIP_MEMORY_SCOPE_AGENT);
    }
    __syncthreads();
    if (slast != 3u) return;
    __threadfence();      // acquire before reading other quarters' fold

    // ---- scan + finalize (one block per seg) ----
    const int n = seg >> 2, b = seg & 3;
    __shared__ float scnt[NSEG];
    __shared__ float sfr[256];
    __shared__ unsigned up[256], un[256];
    __shared__ double sdd[256];
    if (tid < NSEG) scnt[tid] = wsf[D_CNT + tid];
    __syncthreads();

    if (n == 0) {   // per-batch sigma loss + background seed loss
        sfr[tid] = fgp[NI*1024 + b*NSTRIP + tid];   // bg s^2 partials (256 strips)
        __syncthreads();
        #pragma unroll
        for (int d = 128; d > 0; d >>= 1) {
            if (tid < d) sfr[tid] += sfr[tid + d];
            __syncthreads();
        }
        if (tid == 0) {
            float bgs = sfr[0];
            int np = 0; float ss = 0.f, csum = 0.f;
            for (int k = 0; k < NI; ++k) {
                float cv = scnt[k*4 + b];
                csum += cv;
                if (cv > 0.5f) { np++; ss += wsf[D_SL + k*4 + b]; }
            }
            float bgc = fmaxf((float)P - csum, 1.0f);
            float bgl = bgs / bgc;
            float npf = fmaxf((float)np, 1.0f);
            atomicAdd(out, (ss/npf + bgl/(1.0f + (float)np)) * (1.0f/(float)B));
        }
        __syncthreads();
    }

    const float G = scnt[seg];
    if (G < 0.5f) return;   // uniform across block
    int npc = 0;
    #pragma unroll
    for (int k = 0; k < NI; ++k) npc += (scnt[k*4 + b] > 0.5f) ? 1 : 0;

    // fg seed partial reduce (256 strips)
    sfr[tid] = fgp[n*1024 + b*NSTRIP + tid];
    __syncthreads();
    #pragma unroll
    for (int d = 128; d > 0; d >>= 1) {
        if (tid < d) sfr[tid] += sfr[tid + d];
        __syncthreads();
    }
    const float FG = sfr[0];

    // thread t owns key t: sum this quarter's regs + other 3 quarters' folds
    unsigned pos = posk, neg = negk;
    #pragma unroll
    for (int qq = 0; qq < 4; ++qq) {
        if (qq == q) continue;
        pos += fold[((size_t)qq*NSEG + seg)*NB + tid];
        neg += fold[(size_t)4*NSEG*NB + ((size_t)qq*NSEG + seg)*NB + tid];
    }

    // suffix (descending-key) inclusive scan over thread totals
    up[tid] = pos; un[tid] = neg;
    __syncthreads();
    for (int d = 1; d < 256; d <<= 1) {
        unsigned ap = (tid + d < 256) ? up[tid + d] : 0u;
        unsigned an = (tid + d < 256) ? un[tid + d] : 0u;
        __syncthreads();
        up[tid] += ap; un[tid] += an;
        __syncthreads();
    }
    const unsigned TP = up[0], TN = un[0];
    const unsigned Gu = (unsigned)(G + 0.5f);
    const unsigned NEGu = (unsigned)P - Gu;
    unsigned cump = up[tid] - pos;   // counts with key strictly greater
    unsigned cumn = un[tid] - neg;

    const double dG = (double)G;
    double acc = 0.0;
    {
        unsigned cp = pos, cn = neg;
        if (tid == 0) { cp = Gu - TP; cn = NEGu - TN; }  // exact bucket-0
        if (cp | cn) {
            unsigned ep = cump, en = cumn;
            unsigned epi = ep + cp, eni = en + cn;
            double jb = 1.0 - (dG - (double)ep)  / (dG + (double)en);
            double ja = 1.0 - (dG - (double)epi) / (dG + (double)eni);
            acc = (((double)tid + 0.5) * (2.0/(double)NB)) * (ja - jb);
        }
    }
    sdd[tid] = acc;
    __syncthreads();
    #pragma unroll
    for (int d = 128; d > 0; d >>= 1) {
        if (tid < d) sdd[tid] += sdd[tid + d];
        __syncthreads();
    }
    if (tid == 0) {
        float npf = fmaxf((float)npc, 1.0f);
        float val = (float)sdd[0] / (npf * (float)B)
                  + (FG / G) / ((1.0f + (float)npc) * (float)B);
        atomicAdd(out, val);
    }
}

extern "C" void kernel_launch(void* const* d_in, const int* in_sizes, int n_in,
                              void* d_out, int out_size, void* d_ws, size_t ws_size,
                              hipStream_t stream) {
    (void)in_sizes; (void)n_in; (void)out_size; (void)ws_size;
    const float* xv  = (const float*)d_in[0];
    const float* xs  = (const float*)d_in[1];
    const float* xsd = (const float*)d_in[2];
    const int*   t   = (const int*)d_in[3];
    float* wsf = (float*)d_ws;
    unsigned* hist_g = (unsigned*)d_ws + OFF_HIST;
    unsigned* fold   = (unsigned*)d_ws + OFF_FOLD;
    float* pk1 = wsf + OFF_PK1;
    float* fgp = wsf + OFF_FGP;
    float* out = (float*)d_out;

    k1_stats<<<dim3(K1B, B), 256, 0, stream>>>(xv, xs, t, pk1);
    k2_finalize<<<1, 1024, 0, stream>>>(wsf, pk1, out);
    k3_hist<<<dim3(NSTRIP, B), 512, 0, stream>>>(xv, xsd, t, wsf, hist_g, fgp);
    k4_fused<<<dim3(4, NSEG), 256, 0, stream>>>(hist_g, fold, wsf, fgp, out);
}

// Round 15
// 127.836 us; speedup vs baseline: 1.0393x; 1.0058x over previous
//
#include <hip/hip_runtime.h>
#include <math.h>

#define B 4
#define H 512
#define W 1024
#define P (H*W)            // 524288
#define NI 8
#define NSEG 32            // seg = n*B + b
#define NB 256             // histogram buckets over err in [0,2]
#define NSTRIP 256
#define STRIP_PX (P/NSTRIP) // 2048
#define K1B 128             // k1 blocks per batch
#define K1PX (P/K1B)        // 4096 px per k1 block

// ---- ws layout (4-byte units) ----
#define D_K4C  0            // 32 u32 last-block counters (zeroed by k1 block 0)
#define OFF_FGP 64          // 9*1024 floats (rows 0..7 = fg per inst, row 8 = bg s^2)
#define OFF_HIST (OFF_FGP + 9*1024)          // u32: NSEG*NSTRIP*NB = 8 MB
#define OFF_FOLD (OFF_HIST + NSEG*NSTRIP*NB) // u32: 8*NSEG*NB = 256 KB
#define OFF_PK1  (OFF_FOLD + 8*NSEG*NB)      // 512*64 floats = 128 KB

__device__ __forceinline__ float fast_tanh(float x) {
    float e = __expf(2.0f * x);
    return 1.0f - 2.0f / (e + 1.0f);
}
__device__ __forceinline__ float fast_sigmoid(float x) {
    return 1.0f / (1.0f + __expf(-x));
}
template<int CTRL, int RM>
__device__ __forceinline__ float dpp_add(float x) {
    int y = __builtin_amdgcn_update_dpp(0, __float_as_int(x), CTRL, RM, 0xF, true);
    return x + __int_as_float(y);
}
__device__ __forceinline__ float wred(float x) {
    x = dpp_add<0x111, 0xF>(x);   // row_shr:1
    x = dpp_add<0x112, 0xF>(x);   // row_shr:2
    x = dpp_add<0x114, 0xF>(x);   // row_shr:4
    x = dpp_add<0x118, 0xF>(x);   // row_shr:8
    x = dpp_add<0x142, 0xA>(x);   // row_bcast:15
    x = dpp_add<0x143, 0xC>(x);   // row_bcast:31
    return x;                     // lane 63 = wave total
}

// ---------------- K1: per-block partial sums + init counters/out ----
__global__ __launch_bounds__(256) void k1_stats(const float* __restrict__ xv,
                                                const float* __restrict__ xs,
                                                const int*  __restrict__ t,
                                                float* __restrict__ pk1,
                                                unsigned* __restrict__ wsu,
                                                float* __restrict__ out) {
    const int b = blockIdx.y, bx = blockIdx.x, tid = threadIdx.x;
    const int lane = tid & 63, wid = tid >> 6;
    if (bx == 0 && b == 0) {            // zero k4 counters + output (visible at dispatch end)
        if (tid < 32) wsu[D_K4C + tid] = 0u;
        else if (tid == 32) out[0] = 0.f;
    }
    const float* xv_y = xv + (size_t)b*2*P;
    const float* xv_x = xv_y + P;
    const float* xs_y = xs + (size_t)b*2*P;
    const float* xs_x = xs_y + P;
    const int*   tb   = t + (size_t)b*P;

    float cnt[NI], sey[NI], sex[NI], sgy[NI], sgx[NI], sq[NI];
    #pragma unroll
    for (int n = 0; n < NI; ++n) { cnt[n]=0.f; sey[n]=0.f; sex[n]=0.f; sgy[n]=0.f; sgx[n]=0.f; sq[n]=0.f; }

    #pragma unroll
    for (int it = 0; it < 4; ++it) {
        int p0 = bx*K1PX + it*1024 + tid*4;
        float4 vy = *(const float4*)(xv_y + p0);
        float4 vx = *(const float4*)(xv_x + p0);
        float4 sy = *(const float4*)(xs_y + p0);
        float4 sx = *(const float4*)(xs_x + p0);
        int4   tt = *(const int4*)(tb + p0);
        #pragma unroll
        for (int j = 0; j < 4; ++j) {
            int pix = p0 + j;
            float ey = fast_tanh((&vy.x)[j]) + (float)(pix >> 10) * (1.0f/1024.0f);
            float ex = fast_tanh((&vx.x)[j]) + (float)(pix & 1023) * (1.0f/1024.0f);
            float gy = (&sy.x)[j], gx = (&sx.x)[j];
            int tv = (&tt.x)[j];
            float q = gy*gy + gx*gx;
            #pragma unroll
            for (int n = 0; n < NI; ++n) {
                float m = (tv == n+1) ? 1.0f : 0.0f;
                cnt[n] += m; sey[n] += m*ey; sex[n] += m*ex;
                sgy[n] += m*gy; sgx[n] += m*gx; sq[n] += m*q;
            }
        }
    }
    __shared__ float sw[4*64];
    #define RED48(val, slot) { float r_ = wred(val); if (lane == 63) sw[wid*64 + (slot)] = r_; }
    #pragma unroll
    for (int n = 0; n < NI; ++n) {
        RED48(cnt[n], n*6+0); RED48(sey[n], n*6+1); RED48(sex[n], n*6+2);
        RED48(sgy[n], n*6+3); RED48(sgx[n], n*6+4); RED48(sq[n],  n*6+5);
    }
    #undef RED48
    __syncthreads();
    if (tid < 48) {
        float s = sw[tid] + sw[64+tid] + sw[128+tid] + sw[192+tid];
        pk1[(size_t)(b*K1B + bx)*64 + tid] = s;   // coalesced row per block
    }
}

// ---------------- K3: derive params locally + 8-instance LDS histograms ----------------
__global__ __launch_bounds__(512) void k3_hist(const float* __restrict__ xv,
                                               const float* __restrict__ xseed,
                                               const int*  __restrict__ t,
                                               const float* __restrict__ pk1,
                                               unsigned* __restrict__ hist_g,
                                               float* __restrict__ fgp) {
    const int strip = blockIdx.x;
    const int b     = blockIdx.y;
    const int tid   = threadIdx.x;
    const int lane  = tid & 63;

    __shared__ unsigned hist[NI*NB];   // 8 KB: pos<<16 | neg
    __shared__ float sred[8*64];       // param-derivation scratch (2 KB)
    __shared__ float spar[4*NI];       // cyp,cxp,ay,ax

    // ---- derive this batch's params from pk1 (redundant per block, ~cheap) ----
    {
        const int v = tid & 63, g = tid >> 6;   // g 0..7
        float acc = 0.f;
        const float* base = pk1 + (size_t)(b*K1B + g*16)*64 + v;
        #pragma unroll
        for (int i = 0; i < 16; ++i) acc += base[(size_t)i*64];
        sred[g*64 + v] = acc;
        __syncthreads();
        if (tid < 64) {
            float s = 0.f;
            #pragma unroll
            for (int g2 = 0; g2 < 8; ++g2) s += sred[g2*64 + tid];
            sred[tid] = s;   // slot totals in sred[0..63]
        }
        __syncthreads();
        if (tid < NI) {
            int n = tid;
            float cv  = sred[n*6+0];
            float sey = sred[n*6+1];
            float sex = sred[n*6+2];
            float sgy = sred[n*6+3];
            float sgx = sred[n*6+4];
            float safe = fmaxf(cv, 1.0f);
            float ipy = sgy/safe, ipx = sgx/safe;
            const float hl2e = 0.7213475204444817f;
            float ayv = sqrtf(expf(10.0f*ipy) * hl2e);
            float axv = sqrtf(expf(10.0f*ipx) * hl2e);
            spar[n]      = ayv*(sey/safe);
            spar[NI+n]   = axv*(sex/safe);
            spar[2*NI+n] = ayv;
            spar[3*NI+n] = axv;
        }
    }
    *((uint4*)hist + tid) = (uint4){0u,0u,0u,0u};
    __syncthreads();

    float cyp[NI], cxp[NI], ay[NI], ax[NI], fgn[NI];
    #pragma unroll
    for (int n = 0; n < NI; ++n) {
        cyp[n] = spar[n]; cxp[n] = spar[NI+n];
        ay[n] = spar[2*NI+n]; ax[n] = spar[3*NI+n];
        fgn[n] = 0.f;
    }
    float bgq = 0.f;

    const float* xv_y = xv + (size_t)b*2*P;
    const float* xv_x = xv_y + P;
    const float* sdp  = xseed + (size_t)b*P;
    const int*   tb   = t + (size_t)b*P;

    {   // single 2048-px iteration
        int p0 = strip * STRIP_PX + tid*4;
        float4 vy = *(const float4*)(xv_y + p0);
        float4 vx = *(const float4*)(xv_x + p0);
        float4 se = *(const float4*)(sdp + p0);
        int4   tt = *(const int4*)(tb + p0);
        #pragma unroll
        for (int j = 0; j < 4; ++j) {
            int pix = p0 + j;
            float ey = fast_tanh((&vy.x)[j]) + (float)(pix >> 10) * (1.0f/1024.0f);
            float ex = fast_tanh((&vx.x)[j]) + (float)(pix & 1023) * (1.0f/1024.0f);
            int tv = (&tt.x)[j];
            float gown = 0.f;
            #pragma unroll
            for (int n = 0; n < NI; ++n) {
                float dyp = fmaf(ey, ay[n], -cyp[n]);
                float dxp = fmaf(ex, ax[n], -cxp[n]);
                float e = fmaf(dxp, dxp, dyp*dyp);      // 0.72135 * dist
                float kg = exp2f(8.0f - e);             // 256 * g
                bool lab = (tv == n+1);
                float sel = lab ? (256.0f - kg) : kg;   // == err*INV_BW exactly
                int key = (int)sel;
                key = key > (NB-1) ? (NB-1) : key;
                // key==0 counts are reconstructed exactly in K4 from totals
                if (key > 0) atomicAdd(&hist[n*NB + key], lab ? 0x10000u : 1u);
                if (lab) gown = kg * 0.00390625f;
            }
            float s = fast_sigmoid((&se.x)[j]);
            if (tv > 0) {
                float d = s - gown;
                float dd = d*d;
                #pragma unroll
                for (int n = 0; n < NI; ++n) fgn[n] += (tv == n+1) ? dd : 0.f;
            } else {
                bgq += s*s;
            }
        }
    }
    __syncthreads();
    // vectorized flush: 1 uint4 per thread (2048 u32 total)
    {
        int lin = tid*4;
        int n = lin >> 8, key = lin & (NB-1);
        uint4 v = *(const uint4*)&hist[lin];
        *(uint4*)&hist_g[((size_t)((n*4 + b)*NSTRIP + strip))*NB + key] = v;
    }
    __shared__ float sfg[NI+1];
    if (tid < NI+1) sfg[tid] = 0.f;
    __syncthreads();
    #pragma unroll
    for (int n = 0; n < NI; ++n) {
        float r = wred(fgn[n]);
        if (lane == 63 && r != 0.f) atomicAdd(&sfg[n], r);   // LDS, 8-way max
    }
    {
        float r = wred(bgq);
        if (lane == 63) atomicAdd(&sfg[NI], r);
    }
    __syncthreads();
    if (tid < NI+1) fgp[tid*1024 + b*NSTRIP + strip] = sfg[tid];  // plain store
}

// ---------------- K4: derive cnt/sl + fold + last-block scan + finalize ----------------
__global__ __launch_bounds__(256) void k4_fused(const unsigned* __restrict__ hist_g,
                                                unsigned* __restrict__ fold,
                                                const float* __restrict__ pk1,
                                                unsigned* __restrict__ wsu,
                                                const float* __restrict__ fgp,
                                                float* __restrict__ out) {
    const int q = blockIdx.x;            // strip quarter 0..3 (64 strips each)
    const int seg = blockIdx.y;          // 0..31
    const int tid = threadIdx.x;         // owns key = tid (NB == 256)
    const int n = seg >> 2, b = seg & 3;

    // ---- derive this batch's cnt/sl from pk1 (redundant, cheap) ----
    __shared__ float sred4[4*64];
    __shared__ float scnt8[NI], ssl8[NI];
    {
        const int v = tid & 63, g = tid >> 6;  // g 0..3
        float acc = 0.f;
        const float* base = pk1 + (size_t)(b*K1B + g*32)*64 + v;
        #pragma unroll
        for (int i = 0; i < 32; ++i) acc += base[(size_t)i*64];
        sred4[g*64 + v] = acc;
        __syncthreads();
        if (tid < 64) {
            float s = sred4[tid] + sred4[64+tid] + sred4[128+tid] + sred4[192+tid];
            sred4[tid] = s;
        }
        __syncthreads();
        if (tid < NI) {
            float cv  = sred4[tid*6+0];
            float sgy = sred4[tid*6+3];
            float sgx = sred4[tid*6+4];
            float sq  = sred4[tid*6+5];
            float safe = fmaxf(cv, 1.0f);
            float ipy = sgy/safe, ipx = sgx/safe;
            scnt8[tid] = cv;
            ssl8[tid]  = sq/safe - (ipy*ipy + ipx*ipx);
        }
        __syncthreads();
    }

    // ---- fold this quarter's 64 strips ----
    unsigned posk, negk;
    {
        const unsigned* src = hist_g + (size_t)(seg*NSTRIP + q*64)*NB + tid;
        unsigned pos = 0u, neg = 0u;
        #pragma unroll 8
        for (int s = 0; s < 64; ++s) {
            unsigned v = src[(size_t)s*NB];          // coalesced across threads
            pos += v >> 16; neg += v & 0xffffu;
        }
        fold[((size_t)q*NSEG + seg)*NB + tid] = pos;
        fold[(size_t)4*NSEG*NB + ((size_t)q*NSEG + seg)*NB + tid] = neg;
        posk = pos; negk = neg;
    }

    // ---- last-block election (counters zeroed by k1) ----
    __shared__ unsigned slast;
    __syncthreads();     // drains this block's fold stores
    if (tid == 0) {
        __threadfence();  // agent-scope release
        slast = __hip_atomic_fetch_add(&wsu[D_K4C + seg], 1u, __ATOMIC_ACQ_REL,
                                       __HIP_MEMORY_SCOPE_AGENT);
    }
    __syncthreads();
    if (slast != 3u) return;
    __threadfence();      // acquire before reading other quarters' fold

    // ---- scan + finalize (one block per seg) ----
    __shared__ float sfr[256];
    __shared__ unsigned up[256], un[256];
    __shared__ double sdd[256];

    if (n == 0) {   // per-batch sigma loss + background seed loss
        sfr[tid] = fgp[NI*1024 + b*NSTRIP + tid];   // bg s^2 partials (256 strips)
        __syncthreads();
        #pragma unroll
        for (int d = 128; d > 0; d >>= 1) {
            if (tid < d) sfr[tid] += sfr[tid + d];
            __syncthreads();
        }
        if (tid == 0) {
            float bgs = sfr[0];
            int np = 0; float ss = 0.f, csum = 0.f;
            for (int k = 0; k < NI; ++k) {
                float cv = scnt8[k];
                csum += cv;
                if (cv > 0.5f) { np++; ss += ssl8[k]; }
            }
            float bgc = fmaxf((float)P - csum, 1.0f);
            float bgl = bgs / bgc;
            float npf = fmaxf((float)np, 1.0f);
            atomicAdd(out, (ss/npf + bgl/(1.0f + (float)np)) * (1.0f/(float)B));
        }
        __syncthreads();
    }

    const float G = scnt8[n];
    if (G < 0.5f) return;   // uniform across block
    int npc = 0;
    #pragma unroll
    for (int k = 0; k < NI; ++k) npc += (scnt8[k] > 0.5f) ? 1 : 0;

    // fg seed partial reduce (256 strips)
    sfr[tid] = fgp[n*1024 + b*NSTRIP + tid];
    __syncthreads();
    #pragma unroll
    for (int d = 128; d > 0; d >>= 1) {
        if (tid < d) sfr[tid] += sfr[tid + d];
        __syncthreads();
    }
    const float FG = sfr[0];

    // thread t owns key t: sum this quarter's regs + other 3 quarters' folds
    unsigned pos = posk, neg = negk;
    #pragma unroll
    for (int qq = 0; qq < 4; ++qq) {
        if (qq == q) continue;
        pos += fold[((size_t)qq*NSEG + seg)*NB + tid];
        neg += fold[(size_t)4*NSEG*NB + ((size_t)qq*NSEG + seg)*NB + tid];
    }

    // suffix (descending-key) inclusive scan over thread totals
    up[tid] = pos; un[tid] = neg;
    __syncthreads();
    for (int d = 1; d < 256; d <<= 1) {
        unsigned ap = (tid + d < 256) ? up[tid + d] : 0u;
        unsigned an = (tid + d < 256) ? un[tid + d] : 0u;
        __syncthreads();
        up[tid] += ap; un[tid] += an;
        __syncthreads();
    }
    const unsigned TP = up[0], TN = un[0];
    const unsigned Gu = (unsigned)(G + 0.5f);
    const unsigned NEGu = (unsigned)P - Gu;
    unsigned cump = up[tid] - pos;   // counts with key strictly greater
    unsigned cumn = un[tid] - neg;

    const double dG = (double)G;
    double acc = 0.0;
    {
        unsigned cp = pos, cn = neg;
        if (tid == 0) { cp = Gu - TP; cn = NEGu - TN; }  // exact bucket-0
        if (cp | cn) {
            unsigned ep = cump, en = cumn;
            unsigned epi = ep + cp, eni = en + cn;
            double jb = 1.0 - (dG - (double)ep)  / (dG + (double)en);
            double ja = 1.0 - (dG - (double)epi) / (dG + (double)eni);
            acc = (((double)tid + 0.5) * (2.0/(double)NB)) * (ja - jb);
        }
    }
    sdd[tid] = acc;
    __syncthreads();
    #pragma unroll
    for (int d = 128; d > 0; d >>= 1) {
        if (tid < d) sdd[tid] += sdd[tid + d];
        __syncthreads();
    }
    if (tid == 0) {
        float npf = fmaxf((float)npc, 1.0f);
        float val = (float)sdd[0] / (npf * (float)B)
                  + (FG / G) / ((1.0f + (float)npc) * (float)B);
        atomicAdd(out, val);
    }
}

extern "C" void kernel_launch(void* const* d_in, const int* in_sizes, int n_in,
                              void* d_out, int out_size, void* d_ws, size_t ws_size,
                              hipStream_t stream) {
    (void)in_sizes; (void)n_in; (void)out_size; (void)ws_size;
    const float* xv  = (const float*)d_in[0];
    const float* xs  = (const float*)d_in[1];
    const float* xsd = (const float*)d_in[2];
    const int*   t   = (const int*)d_in[3];
    unsigned* wsu = (unsigned*)d_ws;
    unsigned* hist_g = wsu + OFF_HIST;
    unsigned* fold   = wsu + OFF_FOLD;
    float* pk1 = (float*)d_ws + OFF_PK1;
    float* fgp = (float*)d_ws + OFF_FGP;
    float* out = (float*)d_out;

    k1_stats<<<dim3(K1B, B), 256, 0, stream>>>(xv, xs, t, pk1, wsu, out);
    k3_hist<<<dim3(NSTRIP, B), 512, 0, stream>>>(xv, xsd, t, pk1, hist_g, fgp);
    k4_fused<<<dim3(4, NSEG), 256, 0, stream>>>(hist_g, fold, pk1, wsu, fgp, out);
}